// Round 10
// baseline (314.983 us; speedup 1.0000x reference)
//
#include <hip/hip_runtime.h>
#include <cstdint>
#include <cmath>

#define L_ 4096
#define D_ 1024
#define H_ 16
#define HD_ 64
#define M_ 4096

typedef __bf16 bf16_t;
typedef __attribute__((ext_vector_type(8))) __bf16 bf16x8;
typedef __attribute__((ext_vector_type(4))) __bf16 bf16x4;
typedef __attribute__((ext_vector_type(4))) float f32x4;

// waitcnt encodings: [3:0]|[15:14]=vmcnt, [6:4]=expcnt, [11:8]=lgkmcnt
#define WAIT_VM0 0x0f70   // vmcnt(0), lgkm/exp unconstrained
#define WAIT_LGKM0 0xc07f // lgkmcnt(0), vm/exp unconstrained

__device__ __forceinline__ f32x4 mfma16(bf16x8 a, bf16x8 b, f32x4 c) {
    return __builtin_amdgcn_mfma_f32_16x16x32_bf16(a, b, c, 0, 0, 0);
}

__device__ __forceinline__ void gload_lds16(const bf16_t* g, bf16_t* l) {
    __builtin_amdgcn_global_load_lds(
        (const __attribute__((address_space(1))) unsigned int*)(g),
        (__attribute__((address_space(3))) unsigned int*)(l), 16, 0, 0);
}

__device__ __forceinline__ float fast_exp2(float x) {
    float r;
    asm volatile("v_exp_f32 %0, %1" : "=v"(r) : "v"(x));
    return r;
}
__device__ __forceinline__ float fast_rcp(float x) {
    float r;
    asm volatile("v_rcp_f32 %0, %1" : "=v"(r) : "v"(x));
    return r;
}
// tanh-GELU via sigmoid: max |err| ~1e-3 (<< 0.1175 threshold)
__device__ __forceinline__ float gelu_f(float v) {
    float t = v * (0.7978845608f + 0.0356774081f * v * v);
    return v * fast_rcp(1.f + fast_exp2(-2.885390082f * t));
}

// ---------------------------------------------------------------------------
// LayerNorm: fp32 (rows x 1024) -> bf16
// ---------------------------------------------------------------------------
__global__ __launch_bounds__(256) void ln_kernel(const float* __restrict__ x,
                                                 const float* __restrict__ g,
                                                 const float* __restrict__ b,
                                                 bf16_t* __restrict__ out) {
    int row = blockIdx.x, tid = threadIdx.x;
    int wave = tid >> 6, lane = tid & 63;
    const f32x4* xr = (const f32x4*)(x + (long)row * D_);
    f32x4 v = xr[tid];
    float s = v.x + v.y + v.z + v.w;
    __shared__ float red[8];
#pragma unroll
    for (int off = 32; off > 0; off >>= 1) s += __shfl_down(s, off, 64);
    if (lane == 0) red[wave] = s;
    __syncthreads();
    float mean = (red[0] + red[1] + red[2] + red[3]) * (1.f / 1024.f);
    float s2 = 0.f;
#pragma unroll
    for (int i = 0; i < 4; i++) { float d = v[i] - mean; s2 += d * d; }
#pragma unroll
    for (int off = 32; off > 0; off >>= 1) s2 += __shfl_down(s2, off, 64);
    __syncthreads();
    if (lane == 0) red[wave] = s2;
    __syncthreads();
    float var = (red[0] + red[1] + red[2] + red[3]) * (1.f / 1024.f);
    float rstd = rsqrtf(var + 1e-5f);
    f32x4 g4 = ((const f32x4*)g)[tid];
    f32x4 b4 = ((const f32x4*)b)[tid];
    bf16x4 o;
#pragma unroll
    for (int i = 0; i < 4; i++) o[i] = (bf16_t)((v[i] - mean) * rstd * g4[i] + b4[i]);
    *(bf16x4*)(out + (long)row * D_ + tid * 4) = o;
}

// ---------------------------------------------------------------------------
// All 4 weight transposes: W (K x N fp32) -> Wt (N x K bf16)
// ---------------------------------------------------------------------------
__global__ __launch_bounds__(256) void transpose_all(
    const float* __restrict__ w_qkv, const float* __restrict__ w_o,
    const float* __restrict__ w_fc0, const float* __restrict__ w_fc1,
    bf16_t* __restrict__ t_qkv, bf16_t* __restrict__ t_o,
    bf16_t* __restrict__ t_fc0, bf16_t* __restrict__ t_fc1) {
    __shared__ float t[32][33];
    int bidx = blockIdx.x;
    const float* W;
    bf16_t* Wt;
    int K, N, tile;
    if (bidx < 3072) { W = w_qkv; Wt = t_qkv; K = 1024; N = 3072; tile = bidx; }
    else if (bidx < 4096) { W = w_o; Wt = t_o; K = 1024; N = 1024; tile = bidx - 3072; }
    else if (bidx < 8192) { W = w_fc0; Wt = t_fc0; K = 1024; N = 4096; tile = bidx - 4096; }
    else { W = w_fc1; Wt = t_fc1; K = 4096; N = 1024; tile = bidx - 8192; }
    int nt = N >> 5;
    int n0 = (tile % nt) * 32, k0 = (tile / nt) * 32;
    int tx = threadIdx.x & 31, ty = threadIdx.x >> 5;
#pragma unroll
    for (int r = 0; r < 32; r += 8)
        t[ty + r][tx] = W[(long)(k0 + ty + r) * N + n0 + tx];
    __syncthreads();
#pragma unroll
    for (int r = 0; r < 32; r += 8)
        Wt[(long)(n0 + ty + r) * K + k0 + tx] = (bf16_t)t[tx][ty + r];
}

// ---------------------------------------------------------------------------
// V transpose: qkv v-part -> Vt[c][l] (1024 x 4096 bf16)
// ---------------------------------------------------------------------------
__global__ __launch_bounds__(256) void vt_kernel(const bf16_t* __restrict__ qkv,
                                                 bf16_t* __restrict__ Vt) {
    __shared__ bf16_t t[32][33];
    int l0 = blockIdx.x * 32, c0 = blockIdx.y * 32;
    int tx = threadIdx.x & 31, ty = threadIdx.x >> 5;
#pragma unroll
    for (int r = 0; r < 32; r += 8)
        t[ty + r][tx] = qkv[(long)(l0 + ty + r) * 3072 + 2048 + c0 + tx];
    __syncthreads();
#pragma unroll
    for (int r = 0; r < 32; r += 8)
        Vt[(long)(c0 + ty + r) * 4096 + l0 + tx] = t[tx][ty + r];
}

// ---------------------------------------------------------------------------
// RoPE on q,k. Q pre-scaled by scale*log2(e) (exp2-domain softmax).
// ---------------------------------------------------------------------------
__global__ __launch_bounds__(256) void rope_kernel(bf16_t* __restrict__ qkv,
                                                   const float* __restrict__ freqs) {
    const float k1 = 0.125f * 1.44269504089f;
    int idx = blockIdx.x * 256 + threadIdx.x;  // L*H*8
    int g = idx & 7;
    int h = (idx >> 3) & 15;
    int l = idx >> 7;
    const float* f = freqs + (long)l * 64 + g * 8;
    f32x4 f0 = ((const f32x4*)f)[0];
    f32x4 f1 = ((const f32x4*)f)[1];
    float c[4] = {f0.x, f0.z, f1.x, f1.z};
    float s[4] = {f0.y, f0.w, f1.y, f1.w};
    bf16_t* qp = qkv + (long)l * 3072 + h * 64 + g * 8;
    bf16x8 q = *(bf16x8*)qp;
    bf16x8 k = *(bf16x8*)(qp + 1024);
    bf16x8 qo, ko;
#pragma unroll
    for (int e = 0; e < 4; e++) {
        float a = (float)q[2 * e], b = (float)q[2 * e + 1];
        qo[2 * e] = (bf16_t)((a * c[e] - b * s[e]) * k1);
        qo[2 * e + 1] = (bf16_t)((a * s[e] + b * c[e]) * k1);
        a = (float)k[2 * e]; b = (float)k[2 * e + 1];
        ko[2 * e] = (bf16_t)(a * c[e] - b * s[e]);
        ko[2 * e + 1] = (bf16_t)(a * s[e] + b * c[e]);
    }
    *(bf16x8*)qp = qo;
    *(bf16x8*)(qp + 1024) = ko;
}

// ===========================================================================
// 256x256 4-phase GEMM (r9): BK=64, 128 KiB LDS, post-MFMA reads, 32 MFMA
// per barrier. (Unchanged from round 9 — see that round's audit.)
// ===========================================================================
#define STAGE_A(d, h, kt)                                                          \
    gload_lds16(aSt + (long)((h) * 128) * K + (kt), &SA[d][h][(wv * 16) * 64]);    \
    gload_lds16(aSt + (long)((h) * 128 + 8) * K + (kt), &SA[d][h][(wv * 16 + 8) * 64]);

#define STAGE_B(d, h, kt)                                                          \
    gload_lds16(bSt + (long)((h) * 128) * K + (kt), &SB[d][h][(wv * 16) * 64]);    \
    gload_lds16(bSt + (long)((h) * 128 + 8) * K + (kt), &SB[d][h][(wv * 16 + 8) * 64]);

#define RD_A(dst, src, rq)                                                          \
    _Pragma("unroll") for (int i_ = 0; i_ < 4; i_++) {                              \
        dst[i_][0] = *(const bf16x8*)&src[((rq) * 64 + i_ * 16 + l16) * 64 + sl0 * 8]; \
        dst[i_][1] = *(const bf16x8*)&src[((rq) * 64 + i_ * 16 + l16) * 64 + sl1 * 8]; \
    }

#define RD_B(dst, src, cq)                                                          \
    _Pragma("unroll") for (int j_ = 0; j_ < 2; j_++) {                              \
        dst[j_][0] = *(const bf16x8*)&src[(bro + (cq) * 32 + j_ * 16 + l16) * 64 + sl0 * 8]; \
        dst[j_][1] = *(const bf16x8*)&src[(bro + (cq) * 32 + j_ * 16 + l16) * 64 + sl1 * 8]; \
    }

#define MFMA_Q(rq, cq, Af, Bf)                                                      \
    _Pragma("unroll") for (int i_ = 0; i_ < 4; i_++)                                \
    _Pragma("unroll") for (int j_ = 0; j_ < 2; j_++) {                              \
        acc[(rq) * 4 + i_][(cq) * 2 + j_] =                                         \
            mfma16(Af[i_][0], Bf[j_][0], acc[(rq) * 4 + i_][(cq) * 2 + j_]);        \
        acc[(rq) * 4 + i_][(cq) * 2 + j_] =                                         \
            mfma16(Af[i_][1], Bf[j_][1], acc[(rq) * 4 + i_][(cq) * 2 + j_]);        \
    }

#define LGKM0() asm volatile("s_waitcnt lgkmcnt(0)" ::: "memory")
#define VMC(n) asm volatile("s_waitcnt vmcnt(" #n ")" ::: "memory")
#define BAR() __builtin_amdgcn_s_barrier()
#define PRIO1() __builtin_amdgcn_s_setprio(1)
#define PRIO0() __builtin_amdgcn_s_setprio(0)

template <int EPI>
__device__ __forceinline__ void gemm256_core(
    const bf16_t* __restrict__ A, const bf16_t* __restrict__ Bt,
    int K, int N, long bm, long bn, int kb, int ke,
    bf16_t* __restrict__ outB, const float* __restrict__ bias) {
    __shared__ __align__(16) bf16_t SA[2][2][128 * 64];
    __shared__ __align__(16) bf16_t SB[2][2][128 * 64];
    int tid = threadIdx.x;
    int wv = tid >> 6, lane = tid & 63;
    int quad = lane >> 4, l16 = lane & 15;
    int wm = wv >> 2, wn = wv & 3;
    int lr = lane >> 3;
    int sc = (lane & 7) ^ (lr & 7);
    int sl0 = quad ^ (l16 & 7);
    int sl1 = (4 + quad) ^ (l16 & 7);
    int bro = (wn & 1) * 64;

    const bf16_t* aSt = A + (bm + wv * 16 + lr) * (long)K + sc * 8;
    const bf16_t* bSt = Bt + (bn + wv * 16 + lr) * (long)K + sc * 8;
    const bf16_t* pa0 = SA[0][wm];
    const bf16_t* pa1 = SA[1][wm];
    const bf16_t* pb0 = SB[0][wn >> 1];
    const bf16_t* pb1 = SB[1][wn >> 1];

    f32x4 acc[8][4];
#pragma unroll
    for (int i = 0; i < 8; i++)
#pragma unroll
        for (int j = 0; j < 4; j++) acc[i][j] = (f32x4){0.f, 0.f, 0.f, 0.f};

    bf16x8 a0[4][2], a1[4][2], b0[2][2], b1[2][2];

    // Prologue: stage d0 (tile kb) and d1 (tile kb+64) fully.
    STAGE_B(0, 0, kb); STAGE_B(0, 1, kb); STAGE_A(0, 0, kb); STAGE_A(0, 1, kb);
    STAGE_B(1, 0, kb + 64); STAGE_B(1, 1, kb + 64);
    STAGE_A(1, 0, kb + 64); STAGE_A(1, 1, kb + 64);
    VMC(8);  // d0 (8 loads) landed
    BAR();
    RD_A(a0, pa0, 0); RD_B(b0, pb0, 0); RD_B(b1, pb0, 1);
    LGKM0();

    for (int k0 = kb; k0 < ke; k0 += 128) {
        int kt2 = (k0 + 128 < ke) ? k0 + 128 : kb;  // wrapped prefetch target
        int kt3 = kt2 + 64;
        // P1: 32 MFMA a0 x (b0,b1) on d0; stage dbuf0-B; read a1(d0)
        BAR(); STAGE_B(0, 0, kt2); STAGE_B(0, 1, kt2);
        PRIO1(); MFMA_Q(0, 0, a0, b0); MFMA_Q(0, 1, a0, b1); PRIO0();
        RD_A(a1, pa0, 1); LGKM0();
        // P2: vmcnt -> d1 landed; 32 MFMA a1 x (b0,b1); stage dbuf0-A;
        //     read a0,b0,b1 <- d1
        VMC(4);
        BAR(); STAGE_A(0, 0, kt2); STAGE_A(0, 1, kt2);
        PRIO1(); MFMA_Q(1, 0, a1, b0); MFMA_Q(1, 1, a1, b1); PRIO0();
        RD_A(a0, pa1, 0); RD_B(b0, pb1, 0); RD_B(b1, pb1, 1); LGKM0();
        // P3: 32 MFMA a0 x (b0,b1) on d1; stage dbuf1-B; read a1(d1)
        BAR(); STAGE_B(1, 0, kt3); STAGE_B(1, 1, kt3);
        PRIO1(); MFMA_Q(0, 0, a0, b0); MFMA_Q(0, 1, a0, b1); PRIO0();
        RD_A(a1, pa1, 1); LGKM0();
        // P4: vmcnt -> d0' landed; 32 MFMA a1 x (b0,b1); stage dbuf1-A;
        //     read a0,b0,b1 <- d0' (next iter's P1 operands)
        VMC(4);
        BAR(); STAGE_A(1, 0, kt3); STAGE_A(1, 1, kt3);
        PRIO1(); MFMA_Q(1, 0, a1, b0); MFMA_Q(1, 1, a1, b1); PRIO0();
        RD_A(a0, pa0, 0); RD_B(b0, pb0, 0); RD_B(b1, pb0, 1); LGKM0();
    }
    VMC(0);  // drain wrapped prefetch

#pragma unroll
    for (int ri = 0; ri < 8; ri++)
#pragma unroll
        for (int cj = 0; cj < 4; cj++)
#pragma unroll
            for (int r = 0; r < 4; r++) {
                long row = bm + wm * 128 + (ri >> 2) * 64 + (ri & 3) * 16 + quad * 4 + r;
                long col = bn + wn * 64 + (cj >> 1) * 32 + (cj & 1) * 16 + l16;
                long idx = row * (long)N + col;
                float v = acc[ri][cj][r];
                if (EPI == 0) {
                    outB[idx] = (bf16_t)v;
                } else {
                    v += bias[col];
                    outB[idx] = (bf16_t)gelu_f(v);
                }
            }
}

// QKV: 16m x 12n tiles, grid 192. XCD g -> (gm=g>>2, gn=g&3); 8m x 3n chunk.
__global__ __launch_bounds__(512) void gemm256_qkv(const bf16_t* __restrict__ A,
                                                   const bf16_t* __restrict__ Bt,
                                                   bf16_t* __restrict__ outB) {
    int g = blockIdx.x & 7, w = blockIdx.x >> 3;  // w in [0,24)
    int gm = g >> 2, gn = g & 3;
    long bm = (long)(gm * 8 + w / 3) * 256;
    long bn = (long)(gn * 3 + w % 3) * 256;
    gemm256_core<0>(A, Bt, 1024, 3072, bm, bn, 0, 1024, outB, nullptr);
}

// FC0: 16m x 16n tiles, grid 256. XCD chunk 8m x 4n. bias+gelu epilogue.
__global__ __launch_bounds__(512) void gemm256_fc0(const bf16_t* __restrict__ A,
                                                   const bf16_t* __restrict__ Bt,
                                                   bf16_t* __restrict__ outB,
                                                   const float* __restrict__ bias) {
    int g = blockIdx.x & 7, w = blockIdx.x >> 3;  // w in [0,32)
    int gm = g >> 2, gn = g & 3;
    long bm = (long)(gm * 8 + (w >> 2)) * 256;
    long bn = (long)(gn * 4 + (w & 3)) * 256;
    gemm256_core<2>(A, Bt, 1024, 4096, bm, bn, 0, 1024, outB, bias);
}

// FC1 split-K=4: 16m x 4n x 4z, grid 256. XCD g -> (z=g>>1, gm=g&1).
// Writes bf16 partial P[z][M][N]; reduce_fc1 sums + bias + residual.
__global__ __launch_bounds__(512) void gemm256_fc1(const bf16_t* __restrict__ A,
                                                   const bf16_t* __restrict__ Bt,
                                                   bf16_t* __restrict__ P) {
    int g = blockIdx.x & 7, w = blockIdx.x >> 3;  // w in [0,32)
    int z = g >> 1, gm = g & 1;
    long bm = (long)(gm * 8 + (w >> 2)) * 256;
    long bn = (long)(w & 3) * 256;
    gemm256_core<0>(A, Bt, 4096, 1024, bm, bn, z * 1024, z * 1024 + 1024,
                    P + (long)z * L_ * D_, nullptr);
}

// out = out(h) + bias[col] + sum_z P_z   (in-place on d_out)
__global__ __launch_bounds__(256) void reduce_fc1(const bf16_t* __restrict__ P,
                                                  const float* __restrict__ bias,
                                                  float* __restrict__ out) {
    long i = (long)blockIdx.x * 256 + threadIdx.x;
    f32x4 b = ((const f32x4*)bias)[i & 255];
    f32x4 v = ((f32x4*)out)[i];
#pragma unroll
    for (int z = 0; z < 4; z++) {
        bf16x4 p = ((const bf16x4*)(P + (long)z * L_ * D_))[i];
#pragma unroll
        for (int e = 0; e < 4; e++) v[e] += (float)p[e];
    }
    v.x += b.x; v.y += b.y; v.z += b.z; v.w += b.w;
    ((f32x4*)out)[i] = v;
}

// ---------------------------------------------------------------------------
// GEMM 128x64 BK=64 swizzled for W_O: id%8 = bm_hi. outF = v + res[idx]
// ---------------------------------------------------------------------------
__global__ __launch_bounds__(256) void gemm_bt64_res(const bf16_t* __restrict__ A,
                                                     const bf16_t* __restrict__ Bt,
                                                     int M, int N, int K,
                                                     float* __restrict__ outF,
                                                     const float* __restrict__ res) {
    __shared__ __align__(16) bf16_t As[128 * 64];
    __shared__ __align__(16) bf16_t Bs[64 * 64];
    int tid = threadIdx.x;
    int wave = tid >> 6, lane = tid & 63;
    int quad = lane >> 4, l16 = lane & 15;

    int g = blockIdx.x & 7, w = blockIdx.x >> 3;
    int bn_i = w & 15, bm_i = g * 4 + (w >> 4);
    long bm = (long)bm_i * 128, bn = (long)bn_i * 64;

    f32x4 acc[2][4];
#pragma unroll
    for (int i = 0; i < 2; i++)
#pragma unroll
        for (int j = 0; j < 4; j++) acc[i][j] = (f32x4){0.f, 0.f, 0.f, 0.f};

    int lr = lane >> 3;
    int sc = (lane & 7) ^ (lr & 7);
    const bf16_t* a_base = A + (bm + wave * 32 + lr) * (long)K + sc * 8;
    const bf16_t* b_base = Bt + (bn + wave * 16 + lr) * (long)K + sc * 8;

    for (int k0 = 0; k0 < K; k0 += 64) {
        __syncthreads();
#pragma unroll
        for (int i = 0; i < 4; i++)
            gload_lds16(a_base + k0 + (long)(8 * i) * K, &As[(wave * 32 + 8 * i) * 64]);
#pragma unroll
        for (int i = 0; i < 2; i++)
            gload_lds16(b_base + k0 + (long)(8 * i) * K, &Bs[(wave * 16 + 8 * i) * 64]);
        __builtin_amdgcn_s_waitcnt(WAIT_VM0);
        __syncthreads();

#pragma unroll
        for (int h = 0; h < 2; h++) {
            int sl = (h * 4 + quad) ^ (l16 & 7);
            bf16x8 af[2], bfr[4];
#pragma unroll
            for (int i = 0; i < 2; i++)
                af[i] = *(const bf16x8*)&As[(wave * 32 + i * 16 + l16) * 64 + sl * 8];
#pragma unroll
            for (int j = 0; j < 4; j++)
                bfr[j] = *(const bf16x8*)&Bs[(j * 16 + l16) * 64 + sl * 8];
#pragma unroll
            for (int i = 0; i < 2; i++)
#pragma unroll
                for (int j = 0; j < 4; j++)
                    acc[i][j] = mfma16(af[i], bfr[j], acc[i][j]);
        }
    }

#pragma unroll
    for (int i = 0; i < 2; i++)
#pragma unroll
        for (int j = 0; j < 4; j++)
#pragma unroll
            for (int r = 0; r < 4; r++) {
                long row = bm + wave * 32 + i * 16 + quad * 4 + r;
                long col = bn + j * 16 + l16;
                long idx = row * (long)N + col;
                outF[idx] = acc[i][j][r] + res[idx];
            }
}

// ---------------------------------------------------------------------------
// Flash attention (r10): 64-row KV tiles, 2-tile LDS ring, counted vmcnt —
// never 0 in the loop. Per tile: {vmcnt(4); BAR; QK+softmax+PV; BAR;
// restage buf[cur] with tile t+2}. Prologue: Q(2)+t0(4)+t1(4) issued,
// vmcnt(8) lands Q. Steady state: 8 outstanding at tile top, vmcnt(4)
// retires exactly tile t (issue order is per-tile grouped). WAR: restage of
// buf[cur] is after the post-compute barrier (all waves done reading). RAW:
// tile t published by vmcnt(4)+BAR at tile top. Tail: t+2>=nt restages
// tile t (in-bounds, never consumed). LDS unchanged (41 KB, 3 blocks/CU).
// 1D grid 1024: id%8 = head&7 so all 16 qt of a (head,seg) share one XCD L2.
// ---------------------------------------------------------------------------
__global__ __launch_bounds__(256) void attn_kernel(const bf16_t* __restrict__ qkv,
                                                   const bf16_t* __restrict__ Vt,
                                                   const int* __restrict__ cu,
                                                   bf16_t* __restrict__ out) {
    __shared__ __align__(16) bf16_t QPs[4 * 16 * 72];  // Q staging, then per-wave P
    __shared__ __align__(16) bf16_t Ks[2][64 * 64];
    __shared__ __align__(16) bf16_t Vs[2][64 * 64];

    int tid = threadIdx.x, wave = tid >> 6, lane = tid & 63;
    int quad = lane >> 4, l16 = lane & 15;

    int g = blockIdx.x & 7, w = blockIdx.x >> 3;
    int head = (w & 1) * 8 + g;
    int qt = (w >> 1) & 15;
    int seg = w >> 5;
    int s0 = cu[seg], s1 = cu[seg + 1];
    int r0 = s0 + qt * 64;
    const long hoff = (long)head * 64;

    bf16_t* Qs = QPs;
    bf16_t* Psw = &QPs[wave * 16 * 72];

    int lr = lane >> 3;
    int sc = (lane & 7) ^ (lr & 7);
    int sl0 = (0 * 4 + quad) ^ (l16 & 7);
    int sl1 = (1 * 4 + quad) ^ (l16 & 7);

    // Q stage (2 loads, issued FIRST so vmcnt(8) below retires them)
#pragma unroll
    for (int i = 0; i < 2; i++) {
        int row = wave * 16 + i * 8 + lr;
        gload_lds16(qkv + (long)(r0 + row) * 3072 + hoff + sc * 8,
                    &Qs[(wave * 16 + i * 8) * 64]);
    }
    // KV tiles 0 and 1 (4 loads each, per-tile grouped issue order)
#pragma unroll
    for (int tp = 0; tp < 2; tp++) {
#pragma unroll
        for (int i = 0; i < 2; i++) {
            int row = wave * 16 + i * 8 + lr;
            long kt = s0 + tp * 64;
            gload_lds16(qkv + (kt + row) * (long)3072 + 1024 + hoff + sc * 8,
                        &Ks[tp][(wave * 16 + i * 8) * 64]);
            gload_lds16(Vt + (hoff + row) * (long)4096 + kt + sc * 8,
                        &Vs[tp][(wave * 16 + i * 8) * 64]);
        }
    }
    VMC(8);  // Q landed
    BAR();
    bf16x8 aq0 = *(const bf16x8*)&Qs[(wave * 16 + l16) * 64 + sl0 * 8];
    bf16x8 aq1 = *(const bf16x8*)&Qs[(wave * 16 + l16) * 64 + sl1 * 8];

    bf16x8 ones;
#pragma unroll
    for (int e = 0; e < 8; e++) ones[e] = (bf16_t)1.0f;

    f32x4 o[4];
#pragma unroll
    for (int j = 0; j < 4; j++) o[j] = (f32x4){0.f, 0.f, 0.f, 0.f};
    f32x4 lacc = (f32x4){0.f, 0.f, 0.f, 0.f};

    int nt = (s1 - s0) >> 6;
    for (int t = 0; t < nt; t++) {
        int cur = t & 1;
        VMC(4);  // tile t fully landed (tile t+1 stays in flight)
        BAR();

        f32x4 sacc[4];
#pragma unroll
        for (int j = 0; j < 4; j++) sacc[j] = (f32x4){0.f, 0.f, 0.f, 0.f};
#pragma unroll
        for (int j = 0; j < 4; j++) {
            bf16x8 b0 = *(const bf16x8*)&Ks[cur][(j * 16 + l16) * 64 + sl0 * 8];
            bf16x8 b1 = *(const bf16x8*)&Ks[cur][(j * 16 + l16) * 64 + sl1 * 8];
            sacc[j] = mfma16(aq0, b0, sacc[j]);
            sacc[j] = mfma16(aq1, b1, sacc[j]);
        }

        // p = exp2(s) -> per-wave P strip (A-layout). Per-wave DS ops are
        // in-order, so WAR vs previous tile's reads is safe.
#pragma unroll
        for (int j = 0; j < 4; j++)
#pragma unroll
            for (int r = 0; r < 4; r++)
                Psw[(quad * 4 + r) * 72 + j * 16 + l16] = (bf16_t)fast_exp2(sacc[j][r]);

        __builtin_amdgcn_s_waitcnt(WAIT_LGKM0);  // own-wave write -> read

        bf16x8 ap0 = *(const bf16x8*)&Psw[l16 * 72 + 0 * 32 + quad * 8];
        bf16x8 ap1 = *(const bf16x8*)&Psw[l16 * 72 + 1 * 32 + quad * 8];
#pragma unroll
        for (int j2 = 0; j2 < 4; j2++) {
            bf16x8 b0 = *(const bf16x8*)&Vs[cur][(j2 * 16 + l16) * 64 + sl0 * 8];
            bf16x8 b1 = *(const bf16x8*)&Vs[cur][(j2 * 16 + l16) * 64 + sl1 * 8];
            o[j2] = mfma16(ap0, b0, o[j2]);
            o[j2] = mfma16(ap1, b1, o[j2]);
        }
        lacc = mfma16(ap0, ones, lacc);
        lacc = mfma16(ap1, ones, lacc);

        BAR();  // all waves done reading buf[cur] -> safe to restage
        int t2 = (t + 2 < nt) ? t + 2 : t;  // tail: redundant in-bounds restage
        long kt2 = s0 + (long)t2 * 64;
#pragma unroll
        for (int i = 0; i < 2; i++) {
            int row = wave * 16 + i * 8 + lr;
            gload_lds16(qkv + (kt2 + row) * (long)3072 + 1024 + hoff + sc * 8,
                        &Ks[cur][(wave * 16 + i * 8) * 64]);
            gload_lds16(Vt + (hoff + row) * (long)4096 + kt2 + sc * 8,
                        &Vs[cur][(wave * 16 + i * 8) * 64]);
        }
    }
    VMC(0);  // drain tail restages before epilogue

#pragma unroll
    for (int r = 0; r < 4; r++) {
        float inv = fast_rcp(lacc[r]);
        int row = r0 + wave * 16 + quad * 4 + r;
#pragma unroll
        for (int j2 = 0; j2 < 4; j2++)
            out[(long)row * 1024 + head * 64 + j2 * 16 + l16] = (bf16_t)(o[j2][r] * inv);
    }
}

// ---------------------------------------------------------------------------
extern "C" void kernel_launch(void* const* d_in, const int* in_sizes, int n_in,
                              void* d_out, int out_size, void* d_ws, size_t ws_size,
                              hipStream_t stream) {
    const float* hidden = (const float*)d_in[0];
    const int* cu = (const int*)d_in[1];
    const float* freqs = (const float*)d_in[2];
    const float* ln0_g = (const float*)d_in[3];
    const float* ln0_b = (const float*)d_in[4];
    const float* ln1_g = (const float*)d_in[5];
    const float* ln1_b = (const float*)d_in[6];
    const float* w_qkv = (const float*)d_in[7];
    const float* w_o = (const float*)d_in[8];
    const float* w_fc0 = (const float*)d_in[9];
    const float* b_fc0 = (const float*)d_in[10];
    const float* w_fc1 = (const float*)d_in[11];
    const float* b_fc1 = (const float*)d_in[12];
    float* out = (float*)d_out;

    char* ws = (char*)d_ws;
    bf16_t* qkv = (bf16_t*)(ws);                             // 24 MB [0,24)
    bf16_t* attn = (bf16_t*)(ws + ((size_t)24 << 20));       //  8 MB [24,32)
    bf16_t* act = (bf16_t*)(ws);                             // 32 MB [0,32) after attn dead
    bf16_t* x_bf = (bf16_t*)(ws + ((size_t)32 << 20));       //  8 MB [32,40)
    bf16_t* Vt = x_bf;
    bf16_t* y_bf = x_bf;
    bf16_t* fc1p = (bf16_t*)(ws + ((size_t)40 << 20));       // 32 MB [40,72)
    bf16_t* wqkvT = (bf16_t*)(ws + ((size_t)72 << 20));      //  6 MB [72,78)
    bf16_t* woT = (bf16_t*)(ws + ((size_t)78 << 20));        //  2 MB [78,80)
    bf16_t* wfc0T = (bf16_t*)(ws + ((size_t)80 << 20));      //  8 MB [80,88)
    bf16_t* wfc1T = (bf16_t*)(ws + ((size_t)88 << 20));      //  8 MB [88,96)
    float* h = out;

    transpose_all<<<12288, 256, 0, stream>>>(w_qkv, w_o, w_fc0, w_fc1,
                                             wqkvT, woT, wfc0T, wfc1T);

    ln_kernel<<<L_, 256, 0, stream>>>(hidden, ln0_g, ln0_b, x_bf);

    // QKV: 256^2 4-phase, grid 192 (16m x 12n)
    gemm256_qkv<<<192, 512, 0, stream>>>(x_bf, wqkvT, qkv);

    rope_kernel<<<(L_ * H_ * 8) / 256, 256, 0, stream>>>(qkv, freqs);
    vt_kernel<<<dim3(4096 / 32, 1024 / 32), 256, 0, stream>>>(qkv, Vt);

    attn_kernel<<<1024, 256, 0, stream>>>(qkv, Vt, cu, attn);

    // h = attn @ W_O + hidden -> d_out; grid 512
    gemm_bt64_res<<<512, 256, 0, stream>>>(
        attn, woT, L_, 1024, 1024, h, hidden);

    ln_kernel<<<L_, 256, 0, stream>>>(h, ln1_g, ln1_b, y_bf);

    // FC0: 256^2 4-phase + bias/gelu, grid 256 (16m x 16n)
    gemm256_fc0<<<256, 512, 0, stream>>>(y_bf, wfc0T, act, b_fc0);

    // FC1: 256^2 4-phase split-K=4, grid 256 (16m x 4n x 4z)
    gemm256_fc1<<<256, 512, 0, stream>>>(act, wfc1T, fc1p);
    reduce_fc1<<<(L_ * D_ / 4) / 256, 256, 0, stream>>>(fc1p, b_fc1, out);
}

// Round 11
// 311.975 us; speedup vs baseline: 1.0096x; 1.0096x over previous
//
#include <hip/hip_runtime.h>
#include <cstdint>
#include <cmath>

#define L_ 4096
#define D_ 1024
#define H_ 16
#define HD_ 64
#define M_ 4096

typedef __bf16 bf16_t;
typedef __attribute__((ext_vector_type(8))) __bf16 bf16x8;
typedef __attribute__((ext_vector_type(4))) __bf16 bf16x4;
typedef __attribute__((ext_vector_type(4))) float f32x4;

// waitcnt encodings: [3:0]|[15:14]=vmcnt, [6:4]=expcnt, [11:8]=lgkmcnt
#define WAIT_VM0 0x0f70   // vmcnt(0), lgkm/exp unconstrained
#define WAIT_LGKM0 0xc07f // lgkmcnt(0), vm/exp unconstrained

__device__ __forceinline__ f32x4 mfma16(bf16x8 a, bf16x8 b, f32x4 c) {
    return __builtin_amdgcn_mfma_f32_16x16x32_bf16(a, b, c, 0, 0, 0);
}

__device__ __forceinline__ void gload_lds16(const bf16_t* g, bf16_t* l) {
    __builtin_amdgcn_global_load_lds(
        (const __attribute__((address_space(1))) unsigned int*)(g),
        (__attribute__((address_space(3))) unsigned int*)(l), 16, 0, 0);
}

__device__ __forceinline__ float fast_exp2(float x) {
    float r;
    asm volatile("v_exp_f32 %0, %1" : "=v"(r) : "v"(x));
    return r;
}
__device__ __forceinline__ float fast_rcp(float x) {
    float r;
    asm volatile("v_rcp_f32 %0, %1" : "=v"(r) : "v"(x));
    return r;
}
// tanh-GELU via sigmoid: max |err| ~1e-3 (<< 0.1175 threshold)
__device__ __forceinline__ float gelu_f(float v) {
    float t = v * (0.7978845608f + 0.0356774081f * v * v);
    return v * fast_rcp(1.f + fast_exp2(-2.885390082f * t));
}

// ---------------------------------------------------------------------------
// LayerNorm: fp32 (rows x 1024) -> bf16
// ---------------------------------------------------------------------------
__global__ __launch_bounds__(256) void ln_kernel(const float* __restrict__ x,
                                                 const float* __restrict__ g,
                                                 const float* __restrict__ b,
                                                 bf16_t* __restrict__ out) {
    int row = blockIdx.x, tid = threadIdx.x;
    int wave = tid >> 6, lane = tid & 63;
    const f32x4* xr = (const f32x4*)(x + (long)row * D_);
    f32x4 v = xr[tid];
    float s = v.x + v.y + v.z + v.w;
    __shared__ float red[8];
#pragma unroll
    for (int off = 32; off > 0; off >>= 1) s += __shfl_down(s, off, 64);
    if (lane == 0) red[wave] = s;
    __syncthreads();
    float mean = (red[0] + red[1] + red[2] + red[3]) * (1.f / 1024.f);
    float s2 = 0.f;
#pragma unroll
    for (int i = 0; i < 4; i++) { float d = v[i] - mean; s2 += d * d; }
#pragma unroll
    for (int off = 32; off > 0; off >>= 1) s2 += __shfl_down(s2, off, 64);
    __syncthreads();
    if (lane == 0) red[wave] = s2;
    __syncthreads();
    float var = (red[0] + red[1] + red[2] + red[3]) * (1.f / 1024.f);
    float rstd = rsqrtf(var + 1e-5f);
    f32x4 g4 = ((const f32x4*)g)[tid];
    f32x4 b4 = ((const f32x4*)b)[tid];
    bf16x4 o;
#pragma unroll
    for (int i = 0; i < 4; i++) o[i] = (bf16_t)((v[i] - mean) * rstd * g4[i] + b4[i]);
    *(bf16x4*)(out + (long)row * D_ + tid * 4) = o;
}

// ---------------------------------------------------------------------------
// All 4 weight transposes: W (K x N fp32) -> Wt (N x K bf16)
// ---------------------------------------------------------------------------
__global__ __launch_bounds__(256) void transpose_all(
    const float* __restrict__ w_qkv, const float* __restrict__ w_o,
    const float* __restrict__ w_fc0, const float* __restrict__ w_fc1,
    bf16_t* __restrict__ t_qkv, bf16_t* __restrict__ t_o,
    bf16_t* __restrict__ t_fc0, bf16_t* __restrict__ t_fc1) {
    __shared__ float t[32][33];
    int bidx = blockIdx.x;
    const float* W;
    bf16_t* Wt;
    int K, N, tile;
    if (bidx < 3072) { W = w_qkv; Wt = t_qkv; K = 1024; N = 3072; tile = bidx; }
    else if (bidx < 4096) { W = w_o; Wt = t_o; K = 1024; N = 1024; tile = bidx - 3072; }
    else if (bidx < 8192) { W = w_fc0; Wt = t_fc0; K = 1024; N = 4096; tile = bidx - 4096; }
    else { W = w_fc1; Wt = t_fc1; K = 4096; N = 1024; tile = bidx - 8192; }
    int nt = N >> 5;
    int n0 = (tile % nt) * 32, k0 = (tile / nt) * 32;
    int tx = threadIdx.x & 31, ty = threadIdx.x >> 5;
#pragma unroll
    for (int r = 0; r < 32; r += 8)
        t[ty + r][tx] = W[(long)(k0 + ty + r) * N + n0 + tx];
    __syncthreads();
#pragma unroll
    for (int r = 0; r < 32; r += 8)
        Wt[(long)(n0 + ty + r) * K + k0 + tx] = (bf16_t)t[tx][ty + r];
}

// ---------------------------------------------------------------------------
// V transpose: qkv v-part -> Vt[c][l] (1024 x 4096 bf16)
// ---------------------------------------------------------------------------
__global__ __launch_bounds__(256) void vt_kernel(const bf16_t* __restrict__ qkv,
                                                 bf16_t* __restrict__ Vt) {
    __shared__ bf16_t t[32][33];
    int l0 = blockIdx.x * 32, c0 = blockIdx.y * 32;
    int tx = threadIdx.x & 31, ty = threadIdx.x >> 5;
#pragma unroll
    for (int r = 0; r < 32; r += 8)
        t[ty + r][tx] = qkv[(long)(l0 + ty + r) * 3072 + 2048 + c0 + tx];
    __syncthreads();
#pragma unroll
    for (int r = 0; r < 32; r += 8)
        Vt[(long)(c0 + ty + r) * 4096 + l0 + tx] = t[tx][ty + r];
}

// ---------------------------------------------------------------------------
// RoPE on q,k. Q pre-scaled by scale*log2(e) (exp2-domain softmax).
// ---------------------------------------------------------------------------
__global__ __launch_bounds__(256) void rope_kernel(bf16_t* __restrict__ qkv,
                                                   const float* __restrict__ freqs) {
    const float k1 = 0.125f * 1.44269504089f;
    int idx = blockIdx.x * 256 + threadIdx.x;  // L*H*8
    int g = idx & 7;
    int h = (idx >> 3) & 15;
    int l = idx >> 7;
    const float* f = freqs + (long)l * 64 + g * 8;
    f32x4 f0 = ((const f32x4*)f)[0];
    f32x4 f1 = ((const f32x4*)f)[1];
    float c[4] = {f0.x, f0.z, f1.x, f1.z};
    float s[4] = {f0.y, f0.w, f1.y, f1.w};
    bf16_t* qp = qkv + (long)l * 3072 + h * 64 + g * 8;
    bf16x8 q = *(bf16x8*)qp;
    bf16x8 k = *(bf16x8*)(qp + 1024);
    bf16x8 qo, ko;
#pragma unroll
    for (int e = 0; e < 4; e++) {
        float a = (float)q[2 * e], b = (float)q[2 * e + 1];
        qo[2 * e] = (bf16_t)((a * c[e] - b * s[e]) * k1);
        qo[2 * e + 1] = (bf16_t)((a * s[e] + b * c[e]) * k1);
        a = (float)k[2 * e]; b = (float)k[2 * e + 1];
        ko[2 * e] = (bf16_t)(a * c[e] - b * s[e]);
        ko[2 * e + 1] = (bf16_t)(a * s[e] + b * c[e]);
    }
    *(bf16x8*)qp = qo;
    *(bf16x8*)(qp + 1024) = ko;
}

// ===========================================================================
// 256x256 4-phase GEMM (r9): BK=64, 128 KiB LDS, post-MFMA reads, 32 MFMA
// per barrier. (Unchanged from round 9 — see that round's audit.)
// ===========================================================================
#define STAGE_A(d, h, kt)                                                          \
    gload_lds16(aSt + (long)((h) * 128) * K + (kt), &SA[d][h][(wv * 16) * 64]);    \
    gload_lds16(aSt + (long)((h) * 128 + 8) * K + (kt), &SA[d][h][(wv * 16 + 8) * 64]);

#define STAGE_B(d, h, kt)                                                          \
    gload_lds16(bSt + (long)((h) * 128) * K + (kt), &SB[d][h][(wv * 16) * 64]);    \
    gload_lds16(bSt + (long)((h) * 128 + 8) * K + (kt), &SB[d][h][(wv * 16 + 8) * 64]);

#define RD_A(dst, src, rq)                                                          \
    _Pragma("unroll") for (int i_ = 0; i_ < 4; i_++) {                              \
        dst[i_][0] = *(const bf16x8*)&src[((rq) * 64 + i_ * 16 + l16) * 64 + sl0 * 8]; \
        dst[i_][1] = *(const bf16x8*)&src[((rq) * 64 + i_ * 16 + l16) * 64 + sl1 * 8]; \
    }

#define RD_B(dst, src, cq)                                                          \
    _Pragma("unroll") for (int j_ = 0; j_ < 2; j_++) {                              \
        dst[j_][0] = *(const bf16x8*)&src[(bro + (cq) * 32 + j_ * 16 + l16) * 64 + sl0 * 8]; \
        dst[j_][1] = *(const bf16x8*)&src[(bro + (cq) * 32 + j_ * 16 + l16) * 64 + sl1 * 8]; \
    }

#define MFMA_Q(rq, cq, Af, Bf)                                                      \
    _Pragma("unroll") for (int i_ = 0; i_ < 4; i_++)                                \
    _Pragma("unroll") for (int j_ = 0; j_ < 2; j_++) {                              \
        acc[(rq) * 4 + i_][(cq) * 2 + j_] =                                         \
            mfma16(Af[i_][0], Bf[j_][0], acc[(rq) * 4 + i_][(cq) * 2 + j_]);        \
        acc[(rq) * 4 + i_][(cq) * 2 + j_] =                                         \
            mfma16(Af[i_][1], Bf[j_][1], acc[(rq) * 4 + i_][(cq) * 2 + j_]);        \
    }

#define LGKM0() asm volatile("s_waitcnt lgkmcnt(0)" ::: "memory")
#define VMC(n) asm volatile("s_waitcnt vmcnt(" #n ")" ::: "memory")
#define BAR() __builtin_amdgcn_s_barrier()
#define PRIO1() __builtin_amdgcn_s_setprio(1)
#define PRIO0() __builtin_amdgcn_s_setprio(0)

template <int EPI>
__device__ __forceinline__ void gemm256_core(
    const bf16_t* __restrict__ A, const bf16_t* __restrict__ Bt,
    int K, int N, long bm, long bn, int kb, int ke,
    bf16_t* __restrict__ outB, const float* __restrict__ bias) {
    __shared__ __align__(16) bf16_t SA[2][2][128 * 64];
    __shared__ __align__(16) bf16_t SB[2][2][128 * 64];
    int tid = threadIdx.x;
    int wv = tid >> 6, lane = tid & 63;
    int quad = lane >> 4, l16 = lane & 15;
    int wm = wv >> 2, wn = wv & 3;
    int lr = lane >> 3;
    int sc = (lane & 7) ^ (lr & 7);
    int sl0 = quad ^ (l16 & 7);
    int sl1 = (4 + quad) ^ (l16 & 7);
    int bro = (wn & 1) * 64;

    const bf16_t* aSt = A + (bm + wv * 16 + lr) * (long)K + sc * 8;
    const bf16_t* bSt = Bt + (bn + wv * 16 + lr) * (long)K + sc * 8;
    const bf16_t* pa0 = SA[0][wm];
    const bf16_t* pa1 = SA[1][wm];
    const bf16_t* pb0 = SB[0][wn >> 1];
    const bf16_t* pb1 = SB[1][wn >> 1];

    f32x4 acc[8][4];
#pragma unroll
    for (int i = 0; i < 8; i++)
#pragma unroll
        for (int j = 0; j < 4; j++) acc[i][j] = (f32x4){0.f, 0.f, 0.f, 0.f};

    bf16x8 a0[4][2], a1[4][2], b0[2][2], b1[2][2];

    // Prologue: stage d0 (tile kb) and d1 (tile kb+64) fully.
    STAGE_B(0, 0, kb); STAGE_B(0, 1, kb); STAGE_A(0, 0, kb); STAGE_A(0, 1, kb);
    STAGE_B(1, 0, kb + 64); STAGE_B(1, 1, kb + 64);
    STAGE_A(1, 0, kb + 64); STAGE_A(1, 1, kb + 64);
    VMC(8);  // d0 (8 loads) landed
    BAR();
    RD_A(a0, pa0, 0); RD_B(b0, pb0, 0); RD_B(b1, pb0, 1);
    LGKM0();

    for (int k0 = kb; k0 < ke; k0 += 128) {
        int kt2 = (k0 + 128 < ke) ? k0 + 128 : kb;  // wrapped prefetch target
        int kt3 = kt2 + 64;
        // P1: 32 MFMA a0 x (b0,b1) on d0; stage dbuf0-B; read a1(d0)
        BAR(); STAGE_B(0, 0, kt2); STAGE_B(0, 1, kt2);
        PRIO1(); MFMA_Q(0, 0, a0, b0); MFMA_Q(0, 1, a0, b1); PRIO0();
        RD_A(a1, pa0, 1); LGKM0();
        // P2: vmcnt -> d1 landed; 32 MFMA a1 x (b0,b1); stage dbuf0-A;
        //     read a0,b0,b1 <- d1
        VMC(4);
        BAR(); STAGE_A(0, 0, kt2); STAGE_A(0, 1, kt2);
        PRIO1(); MFMA_Q(1, 0, a1, b0); MFMA_Q(1, 1, a1, b1); PRIO0();
        RD_A(a0, pa1, 0); RD_B(b0, pb1, 0); RD_B(b1, pb1, 1); LGKM0();
        // P3: 32 MFMA a0 x (b0,b1) on d1; stage dbuf1-B; read a1(d1)
        BAR(); STAGE_B(1, 0, kt3); STAGE_B(1, 1, kt3);
        PRIO1(); MFMA_Q(0, 0, a0, b0); MFMA_Q(0, 1, a0, b1); PRIO0();
        RD_A(a1, pa1, 1); LGKM0();
        // P4: vmcnt -> d0' landed; 32 MFMA a1 x (b0,b1); stage dbuf1-A;
        //     read a0,b0,b1 <- d0' (next iter's P1 operands)
        VMC(4);
        BAR(); STAGE_A(1, 0, kt3); STAGE_A(1, 1, kt3);
        PRIO1(); MFMA_Q(1, 0, a1, b0); MFMA_Q(1, 1, a1, b1); PRIO0();
        RD_A(a0, pa0, 0); RD_B(b0, pb0, 0); RD_B(b1, pb0, 1); LGKM0();
    }
    VMC(0);  // drain wrapped prefetch

#pragma unroll
    for (int ri = 0; ri < 8; ri++)
#pragma unroll
        for (int cj = 0; cj < 4; cj++)
#pragma unroll
            for (int r = 0; r < 4; r++) {
                long row = bm + wm * 128 + (ri >> 2) * 64 + (ri & 3) * 16 + quad * 4 + r;
                long col = bn + wn * 64 + (cj >> 1) * 32 + (cj & 1) * 16 + l16;
                long idx = row * (long)N + col;
                float v = acc[ri][cj][r];
                if (EPI == 0) {
                    outB[idx] = (bf16_t)v;
                } else {
                    v += bias[col];
                    outB[idx] = (bf16_t)gelu_f(v);
                }
            }
}

// QKV: 16m x 12n tiles, grid 192. XCD g -> (gm=g>>2, gn=g&3); 8m x 3n chunk.
__global__ __launch_bounds__(512) void gemm256_qkv(const bf16_t* __restrict__ A,
                                                   const bf16_t* __restrict__ Bt,
                                                   bf16_t* __restrict__ outB) {
    int g = blockIdx.x & 7, w = blockIdx.x >> 3;  // w in [0,24)
    int gm = g >> 2, gn = g & 3;
    long bm = (long)(gm * 8 + w / 3) * 256;
    long bn = (long)(gn * 3 + w % 3) * 256;
    gemm256_core<0>(A, Bt, 1024, 3072, bm, bn, 0, 1024, outB, nullptr);
}

// FC0: 16m x 16n tiles, grid 256. XCD chunk 8m x 4n. bias+gelu epilogue.
__global__ __launch_bounds__(512) void gemm256_fc0(const bf16_t* __restrict__ A,
                                                   const bf16_t* __restrict__ Bt,
                                                   bf16_t* __restrict__ outB,
                                                   const float* __restrict__ bias) {
    int g = blockIdx.x & 7, w = blockIdx.x >> 3;  // w in [0,32)
    int gm = g >> 2, gn = g & 3;
    long bm = (long)(gm * 8 + (w >> 2)) * 256;
    long bn = (long)(gn * 4 + (w & 3)) * 256;
    gemm256_core<2>(A, Bt, 1024, 4096, bm, bn, 0, 1024, outB, bias);
}

// FC1 split-K=4: 16m x 4n x 4z, grid 256. XCD g -> (z=g>>1, gm=g&1).
// Writes bf16 partial P[z][M][N]; reduce_fc1 sums + bias + residual.
__global__ __launch_bounds__(512) void gemm256_fc1(const bf16_t* __restrict__ A,
                                                   const bf16_t* __restrict__ Bt,
                                                   bf16_t* __restrict__ P) {
    int g = blockIdx.x & 7, w = blockIdx.x >> 3;  // w in [0,32)
    int z = g >> 1, gm = g & 1;
    long bm = (long)(gm * 8 + (w >> 2)) * 256;
    long bn = (long)(w & 3) * 256;
    gemm256_core<0>(A, Bt, 4096, 1024, bm, bn, z * 1024, z * 1024 + 1024,
                    P + (long)z * L_ * D_, nullptr);
}

// out = out(h) + bias[col] + sum_z P_z   (in-place on d_out)
__global__ __launch_bounds__(256) void reduce_fc1(const bf16_t* __restrict__ P,
                                                  const float* __restrict__ bias,
                                                  float* __restrict__ out) {
    long i = (long)blockIdx.x * 256 + threadIdx.x;
    f32x4 b = ((const f32x4*)bias)[i & 255];
    f32x4 v = ((f32x4*)out)[i];
#pragma unroll
    for (int z = 0; z < 4; z++) {
        bf16x4 p = ((const bf16x4*)(P + (long)z * L_ * D_))[i];
#pragma unroll
        for (int e = 0; e < 4; e++) v[e] += (float)p[e];
    }
    v.x += b.x; v.y += b.y; v.z += b.z; v.w += b.w;
    ((f32x4*)out)[i] = v;
}

// ---------------------------------------------------------------------------
// GEMM 128x64 BK=64 swizzled for W_O: id%8 = bm_hi. outF = v + res[idx]
// ---------------------------------------------------------------------------
__global__ __launch_bounds__(256) void gemm_bt64_res(const bf16_t* __restrict__ A,
                                                     const bf16_t* __restrict__ Bt,
                                                     int M, int N, int K,
                                                     float* __restrict__ outF,
                                                     const float* __restrict__ res) {
    __shared__ __align__(16) bf16_t As[128 * 64];
    __shared__ __align__(16) bf16_t Bs[64 * 64];
    int tid = threadIdx.x;
    int wave = tid >> 6, lane = tid & 63;
    int quad = lane >> 4, l16 = lane & 15;

    int g = blockIdx.x & 7, w = blockIdx.x >> 3;
    int bn_i = w & 15, bm_i = g * 4 + (w >> 4);
    long bm = (long)bm_i * 128, bn = (long)bn_i * 64;

    f32x4 acc[2][4];
#pragma unroll
    for (int i = 0; i < 2; i++)
#pragma unroll
        for (int j = 0; j < 4; j++) acc[i][j] = (f32x4){0.f, 0.f, 0.f, 0.f};

    int lr = lane >> 3;
    int sc = (lane & 7) ^ (lr & 7);
    const bf16_t* a_base = A + (bm + wave * 32 + lr) * (long)K + sc * 8;
    const bf16_t* b_base = Bt + (bn + wave * 16 + lr) * (long)K + sc * 8;

    for (int k0 = 0; k0 < K; k0 += 64) {
        __syncthreads();
#pragma unroll
        for (int i = 0; i < 4; i++)
            gload_lds16(a_base + k0 + (long)(8 * i) * K, &As[(wave * 32 + 8 * i) * 64]);
#pragma unroll
        for (int i = 0; i < 2; i++)
            gload_lds16(b_base + k0 + (long)(8 * i) * K, &Bs[(wave * 16 + 8 * i) * 64]);
        __builtin_amdgcn_s_waitcnt(WAIT_VM0);
        __syncthreads();

#pragma unroll
        for (int h = 0; h < 2; h++) {
            int sl = (h * 4 + quad) ^ (l16 & 7);
            bf16x8 af[2], bfr[4];
#pragma unroll
            for (int i = 0; i < 2; i++)
                af[i] = *(const bf16x8*)&As[(wave * 32 + i * 16 + l16) * 64 + sl * 8];
#pragma unroll
            for (int j = 0; j < 4; j++)
                bfr[j] = *(const bf16x8*)&Bs[(j * 16 + l16) * 64 + sl * 8];
#pragma unroll
            for (int i = 0; i < 2; i++)
#pragma unroll
                for (int j = 0; j < 4; j++)
                    acc[i][j] = mfma16(af[i], bfr[j], acc[i][j]);
        }
    }

#pragma unroll
    for (int i = 0; i < 2; i++)
#pragma unroll
        for (int j = 0; j < 4; j++)
#pragma unroll
            for (int r = 0; r < 4; r++) {
                long row = bm + wave * 32 + i * 16 + quad * 4 + r;
                long col = bn + j * 16 + l16;
                long idx = row * (long)N + col;
                outF[idx] = acc[i][j][r] + res[idx];
            }
}

// ---------------------------------------------------------------------------
// Flash attention (r11): cross-tile software pipeline (T15). QK(t+1) is
// computed one iteration AHEAD into sB, so tile t's exp2/P-roundtrip/PV
// never waits on just-issued QK MFMAs; QK(t+1) MFMA latency hides under
// tile t's VALU+LDS work. K and V rings stage at different points so the
// top-of-iter wait stays counted:
//   iter t: { VMC(2) [retires V(t),K(t+1); V(t+1) in flight]; BAR;
//             stage K(t+2)->Kbuf[t&1];      // K(t) dead since QK(t) last iter
//             QK(t+1) from Kbuf[(t+1)&1] -> sB;
//             exp2(sA) -> Psw; lgkm0; ap reads;
//             PV(t) from Vbuf[t&1];
//             BAR; stage V(t+2)->Vbuf[t&1]; sA = sB; }
// Ledger (2 loads/stage, in-order): prologue Q(2),K0(2),V0(2),K1(2),V1(2);
// VMC(8)->Q; VMC(6)+BAR->K0; QK(0)->sA. Iter-top VMC(2): outstanding
// {V(t),K(t+1),V(t+1)} -> retires V(t),K(t+1). WAR: K restage double-barrier
// separated from QK(t) reads; V restage after post-PV BAR (r10-validated).
// Tail: clamped redundant restages; final QK discarded (uniform flow).
// ---------------------------------------------------------------------------
__global__ __launch_bounds__(256) void attn_kernel(const bf16_t* __restrict__ qkv,
                                                   const bf16_t* __restrict__ Vt,
                                                   const int* __restrict__ cu,
                                                   bf16_t* __restrict__ out) {
    __shared__ __align__(16) bf16_t QPs[4 * 16 * 72];  // Q staging, then per-wave P
    __shared__ __align__(16) bf16_t Ks[2][64 * 64];
    __shared__ __align__(16) bf16_t Vs[2][64 * 64];

    int tid = threadIdx.x, wave = tid >> 6, lane = tid & 63;
    int quad = lane >> 4, l16 = lane & 15;

    int g = blockIdx.x & 7, w = blockIdx.x >> 3;
    int head = (w & 1) * 8 + g;
    int qt = (w >> 1) & 15;
    int seg = w >> 5;
    int s0 = cu[seg], s1 = cu[seg + 1];
    int r0 = s0 + qt * 64;
    const long hoff = (long)head * 64;

    bf16_t* Qs = QPs;
    bf16_t* Psw = &QPs[wave * 16 * 72];

    int lr = lane >> 3;
    int sc = (lane & 7) ^ (lr & 7);
    int sl0 = (0 * 4 + quad) ^ (l16 & 7);
    int sl1 = (1 * 4 + quad) ^ (l16 & 7);

    // Prologue issue order (matters for the vmcnt ledger):
    // Q(2), K0(2), V0(2), K1(2), V1(2)
#pragma unroll
    for (int i = 0; i < 2; i++) {
        int row = wave * 16 + i * 8 + lr;
        gload_lds16(qkv + (long)(r0 + row) * 3072 + hoff + sc * 8,
                    &Qs[(wave * 16 + i * 8) * 64]);
    }
#pragma unroll
    for (int tp = 0; tp < 2; tp++) {
#pragma unroll
        for (int i = 0; i < 2; i++) {
            int row = wave * 16 + i * 8 + lr;
            long kt = s0 + tp * 64;
            gload_lds16(qkv + (kt + row) * (long)3072 + 1024 + hoff + sc * 8,
                        &Ks[tp][(wave * 16 + i * 8) * 64]);
            gload_lds16(Vt + (hoff + row) * (long)4096 + kt + sc * 8,
                        &Vs[tp][(wave * 16 + i * 8) * 64]);
        }
        // issue order within tp: K then V -> global order Q,K0,V0,K1,V1
    }
    VMC(8);  // Q landed
    BAR();
    bf16x8 aq0 = *(const bf16x8*)&Qs[(wave * 16 + l16) * 64 + sl0 * 8];
    bf16x8 aq1 = *(const bf16x8*)&Qs[(wave * 16 + l16) * 64 + sl1 * 8];

    bf16x8 ones;
#pragma unroll
    for (int e = 0; e < 8; e++) ones[e] = (bf16_t)1.0f;

    f32x4 o[4];
#pragma unroll
    for (int j = 0; j < 4; j++) o[j] = (f32x4){0.f, 0.f, 0.f, 0.f};
    f32x4 lacc = (f32x4){0.f, 0.f, 0.f, 0.f};

    // K0 landed + published; QK(0) -> sA
    VMC(6);
    BAR();
    f32x4 sA[4], sB[4];
#pragma unroll
    for (int j = 0; j < 4; j++) {
        sA[j] = (f32x4){0.f, 0.f, 0.f, 0.f};
        bf16x8 b0 = *(const bf16x8*)&Ks[0][(j * 16 + l16) * 64 + sl0 * 8];
        bf16x8 b1 = *(const bf16x8*)&Ks[0][(j * 16 + l16) * 64 + sl1 * 8];
        sA[j] = mfma16(aq0, b0, sA[j]);
        sA[j] = mfma16(aq1, b1, sA[j]);
    }

    int nt = (s1 - s0) >> 6;
    for (int t = 0; t < nt; t++) {
        int cur = t & 1, nxt = (t + 1) & 1;
        int tK = (t + 2 < nt) ? t + 2 : t;  // clamped (redundant, in-bounds)
        long ktn = s0 + (long)tK * 64;

        VMC(2);  // retires V(t), K(t+1); V(t+1) stays in flight
        BAR();

        // stage K(t+2) -> Kbuf[cur] (K(t) dead: QK(t) ran last iteration)
#pragma unroll
        for (int i = 0; i < 2; i++) {
            int row = wave * 16 + i * 8 + lr;
            gload_lds16(qkv + (ktn + row) * (long)3072 + 1024 + hoff + sc * 8,
                        &Ks[cur][(wave * 16 + i * 8) * 64]);
        }

        // QK(t+1) -> sB (discarded on last iteration; buffer holds valid data)
#pragma unroll
        for (int j = 0; j < 4; j++) {
            sB[j] = (f32x4){0.f, 0.f, 0.f, 0.f};
            bf16x8 b0 = *(const bf16x8*)&Ks[nxt][(j * 16 + l16) * 64 + sl0 * 8];
            bf16x8 b1 = *(const bf16x8*)&Ks[nxt][(j * 16 + l16) * 64 + sl1 * 8];
            sB[j] = mfma16(aq0, b0, sB[j]);
            sB[j] = mfma16(aq1, b1, sB[j]);
        }

        // softmax of tile t (sA is from LAST iteration -> fully complete)
#pragma unroll
        for (int j = 0; j < 4; j++)
#pragma unroll
            for (int r = 0; r < 4; r++)
                Psw[(quad * 4 + r) * 72 + j * 16 + l16] = (bf16_t)fast_exp2(sA[j][r]);

        __builtin_amdgcn_s_waitcnt(WAIT_LGKM0);  // own-wave write -> read

        bf16x8 ap0 = *(const bf16x8*)&Psw[l16 * 72 + 0 * 32 + quad * 8];
        bf16x8 ap1 = *(const bf16x8*)&Psw[l16 * 72 + 1 * 32 + quad * 8];
#pragma unroll
        for (int j2 = 0; j2 < 4; j2++) {
            bf16x8 b0 = *(const bf16x8*)&Vs[cur][(j2 * 16 + l16) * 64 + sl0 * 8];
            bf16x8 b1 = *(const bf16x8*)&Vs[cur][(j2 * 16 + l16) * 64 + sl1 * 8];
            o[j2] = mfma16(ap0, b0, o[j2]);
            o[j2] = mfma16(ap1, b1, o[j2]);
        }
        lacc = mfma16(ap0, ones, lacc);
        lacc = mfma16(ap1, ones, lacc);

        BAR();  // all waves done reading Vbuf[cur] -> safe to restage
#pragma unroll
        for (int i = 0; i < 2; i++) {
            int row = wave * 16 + i * 8 + lr;
            gload_lds16(Vt + (hoff + row) * (long)4096 + ktn + sc * 8,
                        &Vs[cur][(wave * 16 + i * 8) * 64]);
        }

        // rotate pipeline state
#pragma unroll
        for (int j = 0; j < 4; j++) sA[j] = sB[j];
    }
    VMC(0);  // drain tail restages before epilogue

#pragma unroll
    for (int r = 0; r < 4; r++) {
        float inv = fast_rcp(lacc[r]);
        int row = r0 + wave * 16 + quad * 4 + r;
#pragma unroll
        for (int j2 = 0; j2 < 4; j2++)
            out[(long)row * 1024 + head * 64 + j2 * 16 + l16] = (bf16_t)(o[j2][r] * inv);
    }
}

// ---------------------------------------------------------------------------
extern "C" void kernel_launch(void* const* d_in, const int* in_sizes, int n_in,
                              void* d_out, int out_size, void* d_ws, size_t ws_size,
                              hipStream_t stream) {
    const float* hidden = (const float*)d_in[0];
    const int* cu = (const int*)d_in[1];
    const float* freqs = (const float*)d_in[2];
    const float* ln0_g = (const float*)d_in[3];
    const float* ln0_b = (const float*)d_in[4];
    const float* ln1_g = (const float*)d_in[5];
    const float* ln1_b = (const float*)d_in[6];
    const float* w_qkv = (const float*)d_in[7];
    const float* w_o = (const float*)d_in[8];
    const float* w_fc0 = (const float*)d_in[9];
    const float* b_fc0 = (const float*)d_in[10];
    const float* w_fc1 = (const float*)d_in[11];
    const float* b_fc1 = (const float*)d_in[12];
    float* out = (float*)d_out;

    char* ws = (char*)d_ws;
    bf16_t* qkv = (bf16_t*)(ws);                             // 24 MB [0,24)
    bf16_t* attn = (bf16_t*)(ws + ((size_t)24 << 20));       //  8 MB [24,32)
    bf16_t* act = (bf16_t*)(ws);                             // 32 MB [0,32) after attn dead
    bf16_t* x_bf = (bf16_t*)(ws + ((size_t)32 << 20));       //  8 MB [32,40)
    bf16_t* Vt = x_bf;
    bf16_t* y_bf = x_bf;
    bf16_t* fc1p = (bf16_t*)(ws + ((size_t)40 << 20));       // 32 MB [40,72)
    bf16_t* wqkvT = (bf16_t*)(ws + ((size_t)72 << 20));      //  6 MB [72,78)
    bf16_t* woT = (bf16_t*)(ws + ((size_t)78 << 20));        //  2 MB [78,80)
    bf16_t* wfc0T = (bf16_t*)(ws + ((size_t)80 << 20));      //  8 MB [80,88)
    bf16_t* wfc1T = (bf16_t*)(ws + ((size_t)88 << 20));      //  8 MB [88,96)
    float* h = out;

    transpose_all<<<12288, 256, 0, stream>>>(w_qkv, w_o, w_fc0, w_fc1,
                                             wqkvT, woT, wfc0T, wfc1T);

    ln_kernel<<<L_, 256, 0, stream>>>(hidden, ln0_g, ln0_b, x_bf);

    // QKV: 256^2 4-phase, grid 192 (16m x 12n)
    gemm256_qkv<<<192, 512, 0, stream>>>(x_bf, wqkvT, qkv);

    rope_kernel<<<(L_ * H_ * 8) / 256, 256, 0, stream>>>(qkv, freqs);
    vt_kernel<<<dim3(4096 / 32, 1024 / 32), 256, 0, stream>>>(qkv, Vt);

    attn_kernel<<<1024, 256, 0, stream>>>(qkv, Vt, cu, attn);

    // h = attn @ W_O + hidden -> d_out; grid 512
    gemm_bt64_res<<<512, 256, 0, stream>>>(
        attn, woT, L_, 1024, 1024, h, hidden);

    ln_kernel<<<L_, 256, 0, stream>>>(h, ln1_g, ln1_b, y_bf);

    // FC0: 256^2 4-phase + bias/gelu, grid 256 (16m x 16n)
    gemm256_fc0<<<256, 512, 0, stream>>>(y_bf, wfc0T, act, b_fc0);

    // FC1: 256^2 4-phase split-K=4, grid 256 (16m x 4n x 4z)
    gemm256_fc1<<<256, 512, 0, stream>>>(act, wfc1T, fc1p);
    reduce_fc1<<<(L_ * D_ / 4) / 256, 256, 0, stream>>>(fc1p, b_fc1, out);
}

// Round 12
// 299.894 us; speedup vs baseline: 1.0503x; 1.0403x over previous
//
#include <hip/hip_runtime.h>
#include <cstdint>
#include <cmath>

#define L_ 4096
#define D_ 1024
#define H_ 16
#define HD_ 64
#define M_ 4096

typedef __bf16 bf16_t;
typedef __attribute__((ext_vector_type(8))) __bf16 bf16x8;
typedef __attribute__((ext_vector_type(4))) __bf16 bf16x4;
typedef __attribute__((ext_vector_type(4))) float f32x4;

// waitcnt encodings: [3:0]|[15:14]=vmcnt, [6:4]=expcnt, [11:8]=lgkmcnt
#define WAIT_VM0 0x0f70   // vmcnt(0), lgkm/exp unconstrained
#define WAIT_LGKM0 0xc07f // lgkmcnt(0), vm/exp unconstrained

__device__ __forceinline__ f32x4 mfma16(bf16x8 a, bf16x8 b, f32x4 c) {
    return __builtin_amdgcn_mfma_f32_16x16x32_bf16(a, b, c, 0, 0, 0);
}

__device__ __forceinline__ void gload_lds16(const bf16_t* g, bf16_t* l) {
    __builtin_amdgcn_global_load_lds(
        (const __attribute__((address_space(1))) unsigned int*)(g),
        (__attribute__((address_space(3))) unsigned int*)(l), 16, 0, 0);
}

__device__ __forceinline__ float fast_exp2(float x) {
    float r;
    asm volatile("v_exp_f32 %0, %1" : "=v"(r) : "v"(x));
    return r;
}
__device__ __forceinline__ float fast_rcp(float x) {
    float r;
    asm volatile("v_rcp_f32 %0, %1" : "=v"(r) : "v"(x));
    return r;
}
// tanh-GELU via sigmoid: max |err| ~1e-3 (<< 0.1175 threshold)
__device__ __forceinline__ float gelu_f(float v) {
    float t = v * (0.7978845608f + 0.0356774081f * v * v);
    return v * fast_rcp(1.f + fast_exp2(-2.885390082f * t));
}

// ---------------------------------------------------------------------------
// LayerNorm: fp32 (rows x 1024) -> bf16
// ---------------------------------------------------------------------------
__global__ __launch_bounds__(256) void ln_kernel(const float* __restrict__ x,
                                                 const float* __restrict__ g,
                                                 const float* __restrict__ b,
                                                 bf16_t* __restrict__ out) {
    int row = blockIdx.x, tid = threadIdx.x;
    int wave = tid >> 6, lane = tid & 63;
    const f32x4* xr = (const f32x4*)(x + (long)row * D_);
    f32x4 v = xr[tid];
    float s = v.x + v.y + v.z + v.w;
    __shared__ float red[8];
#pragma unroll
    for (int off = 32; off > 0; off >>= 1) s += __shfl_down(s, off, 64);
    if (lane == 0) red[wave] = s;
    __syncthreads();
    float mean = (red[0] + red[1] + red[2] + red[3]) * (1.f / 1024.f);
    float s2 = 0.f;
#pragma unroll
    for (int i = 0; i < 4; i++) { float d = v[i] - mean; s2 += d * d; }
#pragma unroll
    for (int off = 32; off > 0; off >>= 1) s2 += __shfl_down(s2, off, 64);
    __syncthreads();
    if (lane == 0) red[wave] = s2;
    __syncthreads();
    float var = (red[0] + red[1] + red[2] + red[3]) * (1.f / 1024.f);
    float rstd = rsqrtf(var + 1e-5f);
    f32x4 g4 = ((const f32x4*)g)[tid];
    f32x4 b4 = ((const f32x4*)b)[tid];
    bf16x4 o;
#pragma unroll
    for (int i = 0; i < 4; i++) o[i] = (bf16_t)((v[i] - mean) * rstd * g4[i] + b4[i]);
    *(bf16x4*)(out + (long)row * D_ + tid * 4) = o;
}

// ---------------------------------------------------------------------------
// All 4 weight transposes: W (K x N fp32) -> Wt (N x K bf16)
// ---------------------------------------------------------------------------
__global__ __launch_bounds__(256) void transpose_all(
    const float* __restrict__ w_qkv, const float* __restrict__ w_o,
    const float* __restrict__ w_fc0, const float* __restrict__ w_fc1,
    bf16_t* __restrict__ t_qkv, bf16_t* __restrict__ t_o,
    bf16_t* __restrict__ t_fc0, bf16_t* __restrict__ t_fc1) {
    __shared__ float t[32][33];
    int bidx = blockIdx.x;
    const float* W;
    bf16_t* Wt;
    int K, N, tile;
    if (bidx < 3072) { W = w_qkv; Wt = t_qkv; K = 1024; N = 3072; tile = bidx; }
    else if (bidx < 4096) { W = w_o; Wt = t_o; K = 1024; N = 1024; tile = bidx - 3072; }
    else if (bidx < 8192) { W = w_fc0; Wt = t_fc0; K = 1024; N = 4096; tile = bidx - 4096; }
    else { W = w_fc1; Wt = t_fc1; K = 4096; N = 1024; tile = bidx - 8192; }
    int nt = N >> 5;
    int n0 = (tile % nt) * 32, k0 = (tile / nt) * 32;
    int tx = threadIdx.x & 31, ty = threadIdx.x >> 5;
#pragma unroll
    for (int r = 0; r < 32; r += 8)
        t[ty + r][tx] = W[(long)(k0 + ty + r) * N + n0 + tx];
    __syncthreads();
#pragma unroll
    for (int r = 0; r < 32; r += 8)
        Wt[(long)(n0 + ty + r) * K + k0 + tx] = (bf16_t)t[tx][ty + r];
}

// ---------------------------------------------------------------------------
// V transpose: qkv v-part -> Vt'[c][l] (1024 x 4096 bf16), k-PERMUTED within
// each aligned 64-column group so attn's PV B-fragments line up with the
// in-register P A-fragments from swapped QK^T (see attn comment). Within a
// 64-group: half h=w>>5 preserved; within-half 4-groups a=(w>>2)&7 move to
// g = 2*(a&3) + (a>>2) (bijective inverse of A(g)=4*(g&1)+(g>>1)).
// ---------------------------------------------------------------------------
__global__ __launch_bounds__(256) void vt_kernel(const bf16_t* __restrict__ qkv,
                                                 bf16_t* __restrict__ Vt) {
    __shared__ bf16_t t[32][33];
    int l0 = blockIdx.x * 32, c0 = blockIdx.y * 32;
    int tx = threadIdx.x & 31, ty = threadIdx.x >> 5;
#pragma unroll
    for (int r = 0; r < 32; r += 8)
        t[ty + r][tx] = qkv[(long)(l0 + ty + r) * 3072 + 2048 + c0 + tx];
    __syncthreads();
    // permuted destination column for the value V^T[c][l0+tx]
    int w64 = (l0 & 32) + tx;          // position within the aligned 64-group
    int h = w64 >> 5, m = w64 & 31;
    int a = m >> 2, v = m & 3;
    int gp = 2 * (a & 3) + (a >> 2);
    int wp = (l0 & ~63) + 32 * h + 4 * gp + v;
#pragma unroll
    for (int r = 0; r < 32; r += 8)
        Vt[(long)(c0 + ty + r) * 4096 + wp] = t[tx][ty + r];
}

// ---------------------------------------------------------------------------
// RoPE on q,k. Q pre-scaled by scale*log2(e) (exp2-domain softmax).
// ---------------------------------------------------------------------------
__global__ __launch_bounds__(256) void rope_kernel(bf16_t* __restrict__ qkv,
                                                   const float* __restrict__ freqs) {
    const float k1 = 0.125f * 1.44269504089f;
    int idx = blockIdx.x * 256 + threadIdx.x;  // L*H*8
    int g = idx & 7;
    int h = (idx >> 3) & 15;
    int l = idx >> 7;
    const float* f = freqs + (long)l * 64 + g * 8;
    f32x4 f0 = ((const f32x4*)f)[0];
    f32x4 f1 = ((const f32x4*)f)[1];
    float c[4] = {f0.x, f0.z, f1.x, f1.z};
    float s[4] = {f0.y, f0.w, f1.y, f1.w};
    bf16_t* qp = qkv + (long)l * 3072 + h * 64 + g * 8;
    bf16x8 q = *(bf16x8*)qp;
    bf16x8 k = *(bf16x8*)(qp + 1024);
    bf16x8 qo, ko;
#pragma unroll
    for (int e = 0; e < 4; e++) {
        float a = (float)q[2 * e], b = (float)q[2 * e + 1];
        qo[2 * e] = (bf16_t)((a * c[e] - b * s[e]) * k1);
        qo[2 * e + 1] = (bf16_t)((a * s[e] + b * c[e]) * k1);
        a = (float)k[2 * e]; b = (float)k[2 * e + 1];
        ko[2 * e] = (bf16_t)(a * c[e] - b * s[e]);
        ko[2 * e + 1] = (bf16_t)(a * s[e] + b * c[e]);
    }
    *(bf16x8*)qp = qo;
    *(bf16x8*)(qp + 1024) = ko;
}

// ===========================================================================
// 256x256 4-phase GEMM (r9): BK=64, 128 KiB LDS, post-MFMA reads, 32 MFMA
// per barrier. (Unchanged — see round 9 audit.)
// ===========================================================================
#define STAGE_A(d, h, kt)                                                          \
    gload_lds16(aSt + (long)((h) * 128) * K + (kt), &SA[d][h][(wv * 16) * 64]);    \
    gload_lds16(aSt + (long)((h) * 128 + 8) * K + (kt), &SA[d][h][(wv * 16 + 8) * 64]);

#define STAGE_B(d, h, kt)                                                          \
    gload_lds16(bSt + (long)((h) * 128) * K + (kt), &SB[d][h][(wv * 16) * 64]);    \
    gload_lds16(bSt + (long)((h) * 128 + 8) * K + (kt), &SB[d][h][(wv * 16 + 8) * 64]);

#define RD_A(dst, src, rq)                                                          \
    _Pragma("unroll") for (int i_ = 0; i_ < 4; i_++) {                              \
        dst[i_][0] = *(const bf16x8*)&src[((rq) * 64 + i_ * 16 + l16) * 64 + sl0 * 8]; \
        dst[i_][1] = *(const bf16x8*)&src[((rq) * 64 + i_ * 16 + l16) * 64 + sl1 * 8]; \
    }

#define RD_B(dst, src, cq)                                                          \
    _Pragma("unroll") for (int j_ = 0; j_ < 2; j_++) {                              \
        dst[j_][0] = *(const bf16x8*)&src[(bro + (cq) * 32 + j_ * 16 + l16) * 64 + sl0 * 8]; \
        dst[j_][1] = *(const bf16x8*)&src[(bro + (cq) * 32 + j_ * 16 + l16) * 64 + sl1 * 8]; \
    }

#define MFMA_Q(rq, cq, Af, Bf)                                                      \
    _Pragma("unroll") for (int i_ = 0; i_ < 4; i_++)                                \
    _Pragma("unroll") for (int j_ = 0; j_ < 2; j_++) {                              \
        acc[(rq) * 4 + i_][(cq) * 2 + j_] =                                         \
            mfma16(Af[i_][0], Bf[j_][0], acc[(rq) * 4 + i_][(cq) * 2 + j_]);        \
        acc[(rq) * 4 + i_][(cq) * 2 + j_] =                                         \
            mfma16(Af[i_][1], Bf[j_][1], acc[(rq) * 4 + i_][(cq) * 2 + j_]);        \
    }

#define LGKM0() asm volatile("s_waitcnt lgkmcnt(0)" ::: "memory")
#define VMC(n) asm volatile("s_waitcnt vmcnt(" #n ")" ::: "memory")
#define BAR() __builtin_amdgcn_s_barrier()
#define PRIO1() __builtin_amdgcn_s_setprio(1)
#define PRIO0() __builtin_amdgcn_s_setprio(0)

template <int EPI>
__device__ __forceinline__ void gemm256_core(
    const bf16_t* __restrict__ A, const bf16_t* __restrict__ Bt,
    int K, int N, long bm, long bn, int kb, int ke,
    bf16_t* __restrict__ outB, const float* __restrict__ bias) {
    __shared__ __align__(16) bf16_t SA[2][2][128 * 64];
    __shared__ __align__(16) bf16_t SB[2][2][128 * 64];
    int tid = threadIdx.x;
    int wv = tid >> 6, lane = tid & 63;
    int quad = lane >> 4, l16 = lane & 15;
    int wm = wv >> 2, wn = wv & 3;
    int lr = lane >> 3;
    int sc = (lane & 7) ^ (lr & 7);
    int sl0 = quad ^ (l16 & 7);
    int sl1 = (4 + quad) ^ (l16 & 7);
    int bro = (wn & 1) * 64;

    const bf16_t* aSt = A + (bm + wv * 16 + lr) * (long)K + sc * 8;
    const bf16_t* bSt = Bt + (bn + wv * 16 + lr) * (long)K + sc * 8;
    const bf16_t* pa0 = SA[0][wm];
    const bf16_t* pa1 = SA[1][wm];
    const bf16_t* pb0 = SB[0][wn >> 1];
    const bf16_t* pb1 = SB[1][wn >> 1];

    f32x4 acc[8][4];
#pragma unroll
    for (int i = 0; i < 8; i++)
#pragma unroll
        for (int j = 0; j < 4; j++) acc[i][j] = (f32x4){0.f, 0.f, 0.f, 0.f};

    bf16x8 a0[4][2], a1[4][2], b0[2][2], b1[2][2];

    // Prologue: stage d0 (tile kb) and d1 (tile kb+64) fully.
    STAGE_B(0, 0, kb); STAGE_B(0, 1, kb); STAGE_A(0, 0, kb); STAGE_A(0, 1, kb);
    STAGE_B(1, 0, kb + 64); STAGE_B(1, 1, kb + 64);
    STAGE_A(1, 0, kb + 64); STAGE_A(1, 1, kb + 64);
    VMC(8);  // d0 (8 loads) landed
    BAR();
    RD_A(a0, pa0, 0); RD_B(b0, pb0, 0); RD_B(b1, pb0, 1);
    LGKM0();

    for (int k0 = kb; k0 < ke; k0 += 128) {
        int kt2 = (k0 + 128 < ke) ? k0 + 128 : kb;  // wrapped prefetch target
        int kt3 = kt2 + 64;
        // P1: 32 MFMA a0 x (b0,b1) on d0; stage dbuf0-B; read a1(d0)
        BAR(); STAGE_B(0, 0, kt2); STAGE_B(0, 1, kt2);
        PRIO1(); MFMA_Q(0, 0, a0, b0); MFMA_Q(0, 1, a0, b1); PRIO0();
        RD_A(a1, pa0, 1); LGKM0();
        // P2: vmcnt -> d1 landed; 32 MFMA a1 x (b0,b1); stage dbuf0-A;
        //     read a0,b0,b1 <- d1
        VMC(4);
        BAR(); STAGE_A(0, 0, kt2); STAGE_A(0, 1, kt2);
        PRIO1(); MFMA_Q(1, 0, a1, b0); MFMA_Q(1, 1, a1, b1); PRIO0();
        RD_A(a0, pa1, 0); RD_B(b0, pb1, 0); RD_B(b1, pb1, 1); LGKM0();
        // P3: 32 MFMA a0 x (b0,b1) on d1; stage dbuf1-B; read a1(d1)
        BAR(); STAGE_B(1, 0, kt3); STAGE_B(1, 1, kt3);
        PRIO1(); MFMA_Q(0, 0, a0, b0); MFMA_Q(0, 1, a0, b1); PRIO0();
        RD_A(a1, pa1, 1); LGKM0();
        // P4: vmcnt -> d0' landed; 32 MFMA a1 x (b0,b1); stage dbuf1-A;
        //     read a0,b0,b1 <- d0' (next iter's P1 operands)
        VMC(4);
        BAR(); STAGE_A(1, 0, kt3); STAGE_A(1, 1, kt3);
        PRIO1(); MFMA_Q(1, 0, a1, b0); MFMA_Q(1, 1, a1, b1); PRIO0();
        RD_A(a0, pa0, 0); RD_B(b0, pb0, 0); RD_B(b1, pb0, 1); LGKM0();
    }
    VMC(0);  // drain wrapped prefetch

#pragma unroll
    for (int ri = 0; ri < 8; ri++)
#pragma unroll
        for (int cj = 0; cj < 4; cj++)
#pragma unroll
            for (int r = 0; r < 4; r++) {
                long row = bm + wm * 128 + (ri >> 2) * 64 + (ri & 3) * 16 + quad * 4 + r;
                long col = bn + wn * 64 + (cj >> 1) * 32 + (cj & 1) * 16 + l16;
                long idx = row * (long)N + col;
                float v = acc[ri][cj][r];
                if (EPI == 0) {
                    outB[idx] = (bf16_t)v;
                } else {
                    v += bias[col];
                    outB[idx] = (bf16_t)gelu_f(v);
                }
            }
}

// QKV: 16m x 12n tiles, grid 192. XCD g -> (gm=g>>2, gn=g&3); 8m x 3n chunk.
__global__ __launch_bounds__(512) void gemm256_qkv(const bf16_t* __restrict__ A,
                                                   const bf16_t* __restrict__ Bt,
                                                   bf16_t* __restrict__ outB) {
    int g = blockIdx.x & 7, w = blockIdx.x >> 3;  // w in [0,24)
    int gm = g >> 2, gn = g & 3;
    long bm = (long)(gm * 8 + w / 3) * 256;
    long bn = (long)(gn * 3 + w % 3) * 256;
    gemm256_core<0>(A, Bt, 1024, 3072, bm, bn, 0, 1024, outB, nullptr);
}

// FC0: 16m x 16n tiles, grid 256. XCD chunk 8m x 4n. bias+gelu epilogue.
__global__ __launch_bounds__(512) void gemm256_fc0(const bf16_t* __restrict__ A,
                                                   const bf16_t* __restrict__ Bt,
                                                   bf16_t* __restrict__ outB,
                                                   const float* __restrict__ bias) {
    int g = blockIdx.x & 7, w = blockIdx.x >> 3;  // w in [0,32)
    int gm = g >> 2, gn = g & 3;
    long bm = (long)(gm * 8 + (w >> 2)) * 256;
    long bn = (long)(gn * 4 + (w & 3)) * 256;
    gemm256_core<2>(A, Bt, 1024, 4096, bm, bn, 0, 1024, outB, bias);
}

// FC1 split-K=4: 16m x 4n x 4z, grid 256. XCD g -> (z=g>>1, gm=g&1).
// Writes bf16 partial P[z][M][N]; reduce_fc1 sums + bias + residual.
__global__ __launch_bounds__(512) void gemm256_fc1(const bf16_t* __restrict__ A,
                                                   const bf16_t* __restrict__ Bt,
                                                   bf16_t* __restrict__ P) {
    int g = blockIdx.x & 7, w = blockIdx.x >> 3;  // w in [0,32)
    int z = g >> 1, gm = g & 1;
    long bm = (long)(gm * 8 + (w >> 2)) * 256;
    long bn = (long)(w & 3) * 256;
    gemm256_core<0>(A, Bt, 4096, 1024, bm, bn, z * 1024, z * 1024 + 1024,
                    P + (long)z * L_ * D_, nullptr);
}

// out = out(h) + bias[col] + sum_z P_z   (in-place on d_out)
__global__ __launch_bounds__(256) void reduce_fc1(const bf16_t* __restrict__ P,
                                                  const float* __restrict__ bias,
                                                  float* __restrict__ out) {
    long i = (long)blockIdx.x * 256 + threadIdx.x;
    f32x4 b = ((const f32x4*)bias)[i & 255];
    f32x4 v = ((f32x4*)out)[i];
#pragma unroll
    for (int z = 0; z < 4; z++) {
        bf16x4 p = ((const bf16x4*)(P + (long)z * L_ * D_))[i];
#pragma unroll
        for (int e = 0; e < 4; e++) v[e] += (float)p[e];
    }
    v.x += b.x; v.y += b.y; v.z += b.z; v.w += b.w;
    ((f32x4*)out)[i] = v;
}

// ---------------------------------------------------------------------------
// GEMM 128x64 BK=64 swizzled for W_O: id%8 = bm_hi. outF = v + res[idx]
// ---------------------------------------------------------------------------
__global__ __launch_bounds__(256) void gemm_bt64_res(const bf16_t* __restrict__ A,
                                                     const bf16_t* __restrict__ Bt,
                                                     int M, int N, int K,
                                                     float* __restrict__ outF,
                                                     const float* __restrict__ res) {
    __shared__ __align__(16) bf16_t As[128 * 64];
    __shared__ __align__(16) bf16_t Bs[64 * 64];
    int tid = threadIdx.x;
    int wave = tid >> 6, lane = tid & 63;
    int quad = lane >> 4, l16 = lane & 15;

    int g = blockIdx.x & 7, w = blockIdx.x >> 3;
    int bn_i = w & 15, bm_i = g * 4 + (w >> 4);
    long bm = (long)bm_i * 128, bn = (long)bn_i * 64;

    f32x4 acc[2][4];
#pragma unroll
    for (int i = 0; i < 2; i++)
#pragma unroll
        for (int j = 0; j < 4; j++) acc[i][j] = (f32x4){0.f, 0.f, 0.f, 0.f};

    int lr = lane >> 3;
    int sc = (lane & 7) ^ (lr & 7);
    const bf16_t* a_base = A + (bm + wave * 32 + lr) * (long)K + sc * 8;
    const bf16_t* b_base = Bt + (bn + wave * 16 + lr) * (long)K + sc * 8;

    for (int k0 = 0; k0 < K; k0 += 64) {
        __syncthreads();
#pragma unroll
        for (int i = 0; i < 4; i++)
            gload_lds16(a_base + k0 + (long)(8 * i) * K, &As[(wave * 32 + 8 * i) * 64]);
#pragma unroll
        for (int i = 0; i < 2; i++)
            gload_lds16(b_base + k0 + (long)(8 * i) * K, &Bs[(wave * 16 + 8 * i) * 64]);
        __builtin_amdgcn_s_waitcnt(WAIT_VM0);
        __syncthreads();

#pragma unroll
        for (int h = 0; h < 2; h++) {
            int sl = (h * 4 + quad) ^ (l16 & 7);
            bf16x8 af[2], bfr[4];
#pragma unroll
            for (int i = 0; i < 2; i++)
                af[i] = *(const bf16x8*)&As[(wave * 32 + i * 16 + l16) * 64 + sl * 8];
#pragma unroll
            for (int j = 0; j < 4; j++)
                bfr[j] = *(const bf16x8*)&Bs[(j * 16 + l16) * 64 + sl * 8];
#pragma unroll
            for (int i = 0; i < 2; i++)
#pragma unroll
                for (int j = 0; j < 4; j++)
                    acc[i][j] = mfma16(af[i], bfr[j], acc[i][j]);
        }
    }

#pragma unroll
    for (int i = 0; i < 2; i++)
#pragma unroll
        for (int j = 0; j < 4; j++)
#pragma unroll
            for (int r = 0; r < 4; r++) {
                long row = bm + wave * 32 + i * 16 + quad * 4 + r;
                long col = bn + j * 16 + l16;
                long idx = row * (long)N + col;
                outF[idx] = acc[i][j][r] + res[idx];
            }
}

// ---------------------------------------------------------------------------
// Flash attention (r12): SWAPPED QK^T + in-register P. sacc[j] =
// mfma(K_frag_j, Q_frag) gives lane(l16=q, quad) the values
// S[q][k = 16j + 4*quad + r] — the A-fragment pattern under k-permutation
// sigma(8*quad+e) = 16*(e>>2) + 4*quad + (e&3) (per 32-half). P never
// touches LDS: ap0[e] = exp2(sacc[e>>2][e&3]), ap1[e] = exp2(sacc[2+(e>>2)][e&3]).
// V is staged from the sigma-permuted Vt' (see vt_kernel) so PV B-fragments
// see V[sigma(k')][d] — MFMA is invariant under permuting k in both operands.
// Output layout (q=quad*4+r, d=j2*16+l16) and lacc ones-sum unchanged.
// Ring prefetch = r10 structure: 64-row KV tiles, 2-tile ring, VMC(4) at
// tile top (retires tile t; t+1 in flight), restage t+2 after post-PV BAR.
// ---------------------------------------------------------------------------
__global__ __launch_bounds__(256) void attn_kernel(const bf16_t* __restrict__ qkv,
                                                   const bf16_t* __restrict__ Vt,
                                                   const int* __restrict__ cu,
                                                   bf16_t* __restrict__ out) {
    __shared__ __align__(16) bf16_t Qs[64 * 64];
    __shared__ __align__(16) bf16_t Ks[2][64 * 64];
    __shared__ __align__(16) bf16_t Vs[2][64 * 64];

    int tid = threadIdx.x, wave = tid >> 6, lane = tid & 63;
    int quad = lane >> 4, l16 = lane & 15;

    int g = blockIdx.x & 7, w = blockIdx.x >> 3;
    int head = (w & 1) * 8 + g;
    int qt = (w >> 1) & 15;
    int seg = w >> 5;
    int s0 = cu[seg], s1 = cu[seg + 1];
    int r0 = s0 + qt * 64;
    const long hoff = (long)head * 64;

    int lr = lane >> 3;
    int sc = (lane & 7) ^ (lr & 7);
    int sl0 = (0 * 4 + quad) ^ (l16 & 7);
    int sl1 = (1 * 4 + quad) ^ (l16 & 7);

    // Q stage first (vmcnt ledger), then KV tiles 0 and 1
#pragma unroll
    for (int i = 0; i < 2; i++) {
        int row = wave * 16 + i * 8 + lr;
        gload_lds16(qkv + (long)(r0 + row) * 3072 + hoff + sc * 8,
                    &Qs[(wave * 16 + i * 8) * 64]);
    }
#pragma unroll
    for (int tp = 0; tp < 2; tp++) {
#pragma unroll
        for (int i = 0; i < 2; i++) {
            int row = wave * 16 + i * 8 + lr;
            long kt = s0 + tp * 64;
            gload_lds16(qkv + (kt + row) * (long)3072 + 1024 + hoff + sc * 8,
                        &Ks[tp][(wave * 16 + i * 8) * 64]);
            gload_lds16(Vt + (hoff + row) * (long)4096 + kt + sc * 8,
                        &Vs[tp][(wave * 16 + i * 8) * 64]);
        }
    }
    VMC(8);  // Q landed
    BAR();
    bf16x8 aq0 = *(const bf16x8*)&Qs[(wave * 16 + l16) * 64 + sl0 * 8];
    bf16x8 aq1 = *(const bf16x8*)&Qs[(wave * 16 + l16) * 64 + sl1 * 8];

    bf16x8 ones;
#pragma unroll
    for (int e = 0; e < 8; e++) ones[e] = (bf16_t)1.0f;

    f32x4 o[4];
#pragma unroll
    for (int j = 0; j < 4; j++) o[j] = (f32x4){0.f, 0.f, 0.f, 0.f};
    f32x4 lacc = (f32x4){0.f, 0.f, 0.f, 0.f};

    int nt = (s1 - s0) >> 6;
    for (int t = 0; t < nt; t++) {
        int cur = t & 1;
        VMC(4);  // tile t fully landed (tile t+1 stays in flight)
        BAR();

        // QK^T swapped: A = K rows (16j..16j+16), B = Q^T (same regs as aq)
        f32x4 sacc[4];
#pragma unroll
        for (int j = 0; j < 4; j++) {
            sacc[j] = (f32x4){0.f, 0.f, 0.f, 0.f};
            bf16x8 kb0 = *(const bf16x8*)&Ks[cur][(j * 16 + l16) * 64 + sl0 * 8];
            bf16x8 kb1 = *(const bf16x8*)&Ks[cur][(j * 16 + l16) * 64 + sl1 * 8];
            sacc[j] = mfma16(kb0, aq0, sacc[j]);
            sacc[j] = mfma16(kb1, aq1, sacc[j]);
        }

        // in-register P: A-fragments under permuted k (no LDS round-trip)
        bf16x8 ap0, ap1;
#pragma unroll
        for (int e = 0; e < 8; e++) {
            ap0[e] = (bf16_t)fast_exp2(sacc[e >> 2][e & 3]);
            ap1[e] = (bf16_t)fast_exp2(sacc[2 + (e >> 2)][e & 3]);
        }

        // PV with sigma-permuted V (staged from Vt')
#pragma unroll
        for (int j2 = 0; j2 < 4; j2++) {
            bf16x8 bv0 = *(const bf16x8*)&Vs[cur][(j2 * 16 + l16) * 64 + sl0 * 8];
            bf16x8 bv1 = *(const bf16x8*)&Vs[cur][(j2 * 16 + l16) * 64 + sl1 * 8];
            o[j2] = mfma16(ap0, bv0, o[j2]);
            o[j2] = mfma16(ap1, bv1, o[j2]);
        }
        lacc = mfma16(ap0, ones, lacc);
        lacc = mfma16(ap1, ones, lacc);

        BAR();  // all waves done reading tile t buffers -> safe to restage
        int t2 = (t + 2 < nt) ? t + 2 : t;  // tail: redundant in-bounds restage
        long kt2 = s0 + (long)t2 * 64;
#pragma unroll
        for (int i = 0; i < 2; i++) {
            int row = wave * 16 + i * 8 + lr;
            gload_lds16(qkv + (kt2 + row) * (long)3072 + 1024 + hoff + sc * 8,
                        &Ks[cur][(wave * 16 + i * 8) * 64]);
            gload_lds16(Vt + (hoff + row) * (long)4096 + kt2 + sc * 8,
                        &Vs[cur][(wave * 16 + i * 8) * 64]);
        }
    }
    VMC(0);  // drain tail restages before epilogue

#pragma unroll
    for (int r = 0; r < 4; r++) {
        float inv = fast_rcp(lacc[r]);
        int row = r0 + wave * 16 + quad * 4 + r;
#pragma unroll
        for (int j2 = 0; j2 < 4; j2++)
            out[(long)row * 1024 + head * 64 + j2 * 16 + l16] = (bf16_t)(o[j2][r] * inv);
    }
}

// ---------------------------------------------------------------------------
extern "C" void kernel_launch(void* const* d_in, const int* in_sizes, int n_in,
                              void* d_out, int out_size, void* d_ws, size_t ws_size,
                              hipStream_t stream) {
    const float* hidden = (const float*)d_in[0];
    const int* cu = (const int*)d_in[1];
    const float* freqs = (const float*)d_in[2];
    const float* ln0_g = (const float*)d_in[3];
    const float* ln0_b = (const float*)d_in[4];
    const float* ln1_g = (const float*)d_in[5];
    const float* ln1_b = (const float*)d_in[6];
    const float* w_qkv = (const float*)d_in[7];
    const float* w_o = (const float*)d_in[8];
    const float* w_fc0 = (const float*)d_in[9];
    const float* b_fc0 = (const float*)d_in[10];
    const float* w_fc1 = (const float*)d_in[11];
    const float* b_fc1 = (const float*)d_in[12];
    float* out = (float*)d_out;

    char* ws = (char*)d_ws;
    bf16_t* qkv = (bf16_t*)(ws);                             // 24 MB [0,24)
    bf16_t* attn = (bf16_t*)(ws + ((size_t)24 << 20));       //  8 MB [24,32)
    bf16_t* act = (bf16_t*)(ws);                             // 32 MB [0,32) after attn dead
    bf16_t* x_bf = (bf16_t*)(ws + ((size_t)32 << 20));       //  8 MB [32,40)
    bf16_t* Vt = x_bf;
    bf16_t* y_bf = x_bf;
    bf16_t* fc1p = (bf16_t*)(ws + ((size_t)40 << 20));       // 32 MB [40,72)
    bf16_t* wqkvT = (bf16_t*)(ws + ((size_t)72 << 20));      //  6 MB [72,78)
    bf16_t* woT = (bf16_t*)(ws + ((size_t)78 << 20));        //  2 MB [78,80)
    bf16_t* wfc0T = (bf16_t*)(ws + ((size_t)80 << 20));      //  8 MB [80,88)
    bf16_t* wfc1T = (bf16_t*)(ws + ((size_t)88 << 20));      //  8 MB [88,96)
    float* h = out;

    transpose_all<<<12288, 256, 0, stream>>>(w_qkv, w_o, w_fc0, w_fc1,
                                             wqkvT, woT, wfc0T, wfc1T);

    ln_kernel<<<L_, 256, 0, stream>>>(hidden, ln0_g, ln0_b, x_bf);

    // QKV: 256^2 4-phase, grid 192 (16m x 12n)
    gemm256_qkv<<<192, 512, 0, stream>>>(x_bf, wqkvT, qkv);

    rope_kernel<<<(L_ * H_ * 8) / 256, 256, 0, stream>>>(qkv, freqs);
    vt_kernel<<<dim3(4096 / 32, 1024 / 32), 256, 0, stream>>>(qkv, Vt);

    attn_kernel<<<1024, 256, 0, stream>>>(qkv, Vt, cu, attn);

    // h = attn @ W_O + hidden -> d_out; grid 512
    gemm_bt64_res<<<512, 256, 0, stream>>>(
        attn, woT, L_, 1024, 1024, h, hidden);

    ln_kernel<<<L_, 256, 0, stream>>>(h, ln1_g, ln1_b, y_bf);

    // FC0: 256^2 4-phase + bias/gelu, grid 256 (16m x 16n)
    gemm256_fc0<<<256, 512, 0, stream>>>(y_bf, wfc0T, act, b_fc0);

    // FC1: 256^2 4-phase split-K=4, grid 256 (16m x 4n x 4z)
    gemm256_fc1<<<256, 512, 0, stream>>>(act, wfc1T, fc1p);
    reduce_fc1<<<(L_ * D_ / 4) / 256, 256, 0, stream>>>(fc1p, b_fc1, out);
}